// Round 1
// baseline (710.330 us; speedup 1.0000x reference)
//
#include <hip/hip_runtime.h>
#include <math.h>

// Problem constants (from reference)
#define DD 8      // channels
#define HH 4      // heads
#define EE 4      // head dim
#define NLAYER 4
#define BB 4
#define SS 20
#define IMM 64

// z layout: (B, S, IM, IM, D), D innermost.
// strides (floats): b: 655360, s: 32768, i: 512, j: 8
static constexpr int NPOS = BB * SS * IMM * IMM;          // 327680
static constexpr size_t ZBYTES = (size_t)NPOS * DD * 4;   // 10485760

// ---------------------------------------------------------------------------
// emb: xt[b,s,i,j,d] = relu(x[b,s,i,j]*conv_w[d]) + pos_s[s,d] + pos_h[d,i] + pos_w[d,j]
__global__ __launch_bounds__(256)
void emb_kernel(const float* __restrict__ x, const float* __restrict__ conv_w,
                const float* __restrict__ pos_s, const float* __restrict__ pos_h,
                const float* __restrict__ pos_w, float* __restrict__ xt) {
    int idx = blockIdx.x * 256 + threadIdx.x;   // position (b,s,i,j)
    if (idx >= NPOS) return;
    int j = idx & 63;
    int i = (idx >> 6) & 63;
    int s = (idx >> 12) % SS;
    float xv = x[idx];
    float o[8];
#pragma unroll
    for (int d = 0; d < 8; ++d) {
        float v = xv * conv_w[d];
        v = v > 0.f ? v : 0.f;
        o[d] = v + pos_s[s * 8 + d] + pos_h[d * 64 + i] + pos_w[d * 64 + j];
    }
    float4* dst = (float4*)(xt + (size_t)idx * 8);
    dst[0] = make_float4(o[0], o[1], o[2], o[3]);
    dst[1] = make_float4(o[4], o[5], o[6], o[7]);
}

// ---------------------------------------------------------------------------
// One axis-attention over a line of length L. One block per line, 256 threads.
// Line base = b*655360 + u1*m1 + u0*m0 ; element stride = `stride` floats.
template <int L, bool ACCUM>
__global__ __launch_bounds__(256)
void attn_kernel(const float* __restrict__ src, float* __restrict__ dst,
                 const float* __restrict__ Wq, const float* __restrict__ Wkv,
                 const float* __restrict__ Wo, const float* __restrict__ bo,
                 int m0, int c1, int m1, int stride) {
    __shared__ float zl[L][8];      // line channels
    __shared__ float kv[L][32];     // k (0..15) | v (16..31)
    __shared__ float ol[L][17];     // attention output (padded: bank safety)
    __shared__ float wq_s[128];     // 8x16
    __shared__ float wkv_s[256];    // 8x32
    __shared__ float wo_s[128];     // 16x8
    __shared__ float bo_s[8];

    const int t = threadIdx.x;
    if (t < 128) wq_s[t] = Wq[t];
    wkv_s[t] = Wkv[t];
    if (t < 128) wo_s[t] = Wo[t];
    if (t < 8)   bo_s[t] = bo[t];

    const int lid = blockIdx.x;
    const int u0 = lid & 63;
    const int rest = lid >> 6;
    const int u1 = rest % c1;
    const int b  = rest / c1;
    const size_t base = (size_t)b * 655360 + (size_t)u1 * m1 + (size_t)u0 * m0;

    // stage line into LDS
    for (int e = t; e < L * 8; e += 256) {
        int pos = e >> 3, d = e & 7;
        zl[pos][d] = src[base + (size_t)pos * stride + d];
    }
    __syncthreads();

    // K,V projection: kv[pos][c] = sum_d zl[pos][d] * Wkv[d][c]
    for (int e = t; e < L * 32; e += 256) {
        int pos = e >> 5, c = e & 31;
        float acc = 0.f;
#pragma unroll
        for (int d = 0; d < 8; ++d) acc += zl[pos][d] * wkv_s[d * 32 + c];
        kv[pos][c] = acc;
    }
    __syncthreads();

    // Attention: one thread per (head h, query row i)
    if (t < HH * L) {
        const int i = t % L;
        const int h = t / L;
        float qe[4];
#pragma unroll
        for (int e = 0; e < 4; ++e) {
            float acc = 0.f;
#pragma unroll
            for (int d = 0; d < 8; ++d) acc += zl[i][d] * wq_s[d * 16 + h * 4 + e];
            qe[e] = acc;
        }
        float dots[L];
        float m = -1e30f;
#pragma unroll
        for (int j = 0; j < L; ++j) {
            float acc = 0.f;
#pragma unroll
            for (int e = 0; e < 4; ++e) acc += qe[e] * kv[j][h * 4 + e];
            acc *= 0.5f;               // E^-0.5, E=4
            dots[j] = acc;
            m = fmaxf(m, acc);
        }
        float sum = 0.f;
#pragma unroll
        for (int j = 0; j < L; ++j) {
            float p = __expf(dots[j] - m);
            dots[j] = p;
            sum += p;
        }
        const float inv = 1.f / sum;
        float oe[4] = {0.f, 0.f, 0.f, 0.f};
#pragma unroll
        for (int j = 0; j < L; ++j) {
            float p = dots[j] * inv;
#pragma unroll
            for (int e = 0; e < 4; ++e) oe[e] += p * kv[j][16 + h * 4 + e];
        }
#pragma unroll
        for (int e = 0; e < 4; ++e) ol[i][h * 4 + e] = oe[e];
    }
    __syncthreads();

    // Output projection + (optional) accumulate into dst
    for (int e = t; e < L * 8; e += 256) {
        int pos = e >> 3, d = e & 7;
        float acc = bo_s[d];
#pragma unroll
        for (int c = 0; c < 16; ++c) acc += ol[pos][c] * wo_s[c * 8 + d];
        size_t gi = base + (size_t)pos * stride + d;
        if (ACCUM) dst[gi] += acc;
        else       dst[gi] = acc;
    }
}

// ---------------------------------------------------------------------------
// Epilogue part 1: per (b,i,j) -> max over s of (z + xt), dot with Wc, block
// reduce, atomicAdd into accum[b].
__global__ __launch_bounds__(256)
void reduce_kernel(const float* __restrict__ z, const float* __restrict__ xt,
                   const float* __restrict__ Wc, float* __restrict__ accum) {
    const int b  = blockIdx.x >> 4;                        // 16 blocks per b
    const int ij = ((blockIdx.x & 15) << 8) + threadIdx.x; // 0..4095
    float4 m0 = make_float4(-1e30f, -1e30f, -1e30f, -1e30f);
    float4 m1 = m0;
    for (int s = 0; s < SS; ++s) {
        size_t off = (((size_t)(b * SS + s)) * 4096 + ij) * 8;
        float4 a0 = *(const float4*)(z + off);
        float4 a1 = *(const float4*)(z + off + 4);
        float4 c0 = *(const float4*)(xt + off);
        float4 c1 = *(const float4*)(xt + off + 4);
        m0.x = fmaxf(m0.x, a0.x + c0.x); m0.y = fmaxf(m0.y, a0.y + c0.y);
        m0.z = fmaxf(m0.z, a0.z + c0.z); m0.w = fmaxf(m0.w, a0.w + c0.w);
        m1.x = fmaxf(m1.x, a1.x + c1.x); m1.y = fmaxf(m1.y, a1.y + c1.y);
        m1.z = fmaxf(m1.z, a1.z + c1.z); m1.w = fmaxf(m1.w, a1.w + c1.w);
    }
    float partial =
        m0.x * Wc[0 * 4096 + ij] + m0.y * Wc[1 * 4096 + ij] +
        m0.z * Wc[2 * 4096 + ij] + m0.w * Wc[3 * 4096 + ij] +
        m1.x * Wc[4 * 4096 + ij] + m1.y * Wc[5 * 4096 + ij] +
        m1.z * Wc[6 * 4096 + ij] + m1.w * Wc[7 * 4096 + ij];

    __shared__ float red[256];
    red[threadIdx.x] = partial;
    __syncthreads();
#pragma unroll
    for (int off = 128; off > 0; off >>= 1) {
        if (threadIdx.x < off) red[threadIdx.x] += red[threadIdx.x + off];
        __syncthreads();
    }
    if (threadIdx.x == 0) atomicAdd(&accum[b], red[0]);
}

__global__ void final_kernel(const float* __restrict__ accum,
                             const float* __restrict__ bc,
                             float* __restrict__ out) {
    int b = threadIdx.x;
    if (b < BB) out[b] = 1.f / (1.f + expf(-(accum[b] + bc[0])));
}

// ---------------------------------------------------------------------------
extern "C" void kernel_launch(void* const* d_in, const int* in_sizes, int n_in,
                              void* d_out, int out_size, void* d_ws, size_t ws_size,
                              hipStream_t stream) {
    const float* x      = (const float*)d_in[0];
    const float* conv_w = (const float*)d_in[1];
    const float* pos_s  = (const float*)d_in[2];
    const float* pos_h  = (const float*)d_in[3];
    const float* pos_w  = (const float*)d_in[4];
    const float* Wq     = (const float*)d_in[5];
    const float* Wkv    = (const float*)d_in[6];
    const float* Wo     = (const float*)d_in[7];
    const float* bo     = (const float*)d_in[8];
    const float* Wc     = (const float*)d_in[9];
    const float* bc     = (const float*)d_in[10];
    float* out = (float*)d_out;

    char* ws = (char*)d_ws;
    float* xt    = (float*)(ws);
    float* zA    = (float*)(ws + ZBYTES);
    float* zB    = (float*)(ws + 2 * ZBYTES);
    float* accum = (float*)(ws + 3 * ZBYTES);

    emb_kernel<<<NPOS / 256, 256, 0, stream>>>(x, conv_w, pos_s, pos_h, pos_w, xt);

    const float* cur = xt;
    float* bufs[2] = {zA, zB};
    int w = 0;
    for (int l = 0; l < NLAYER; ++l) {
        float* dstp = bufs[w];
        const float* wq0  = Wq  + (size_t)(l * 3 + 0) * 128;
        const float* wkv0 = Wkv + (size_t)(l * 3 + 0) * 256;
        const float* wo0  = Wo  + (size_t)(l * 3 + 0) * 128;
        const float* bo0  = bo  + (size_t)(l * 3 + 0) * 8;
        // a=0: attention over s (L=20), lines (b,i,j): u0=j(m0=8), u1=i(c1=64,m1=512), stride=32768
        attn_kernel<SS, false><<<BB * IMM * IMM, 256, 0, stream>>>(
            cur, dstp, wq0, wkv0, wo0, bo0, 8, 64, 512, 32768);
        // a=1: attention over i (L=64), lines (b,s,j): u0=j(m0=8), u1=s(c1=20,m1=32768), stride=512
        attn_kernel<IMM, true><<<BB * SS * IMM, 256, 0, stream>>>(
            cur, dstp, wq0 + 128, wkv0 + 256, wo0 + 128, bo0 + 8, 8, 20, 32768, 512);
        // a=2: attention over j (L=64), lines (b,s,i): u0=i(m0=512), u1=s(c1=20,m1=32768), stride=8
        attn_kernel<IMM, true><<<BB * SS * IMM, 256, 0, stream>>>(
            cur, dstp, wq0 + 256, wkv0 + 512, wo0 + 256, bo0 + 16, 512, 20, 32768, 8);
        cur = dstp;
        w ^= 1;
    }

    hipMemsetAsync(accum, 0, BB * sizeof(float), stream);
    reduce_kernel<<<BB * 16, 256, 0, stream>>>(cur, xt, Wc, accum);
    final_kernel<<<1, 64, 0, stream>>>(accum, bc, out);
}

// Round 2
// 552.342 us; speedup vs baseline: 1.2860x; 1.2860x over previous
//
#include <hip/hip_runtime.h>
#include <math.h>

#define DD 8
#define HH 4
#define EE 4
#define NLAYER 4
#define BB 4
#define SS 20
#define IMM 64

static constexpr int NPOS = BB * SS * IMM * IMM;          // 327680
static constexpr size_t ZBYTES = (size_t)NPOS * DD * 4;   // 10485760

// ---------------------------------------------------------------------------
__global__ __launch_bounds__(256)
void emb_kernel(const float* __restrict__ x, const float* __restrict__ conv_w,
                const float* __restrict__ pos_s, const float* __restrict__ pos_h,
                const float* __restrict__ pos_w, float* __restrict__ xt) {
    int idx = blockIdx.x * 256 + threadIdx.x;
    if (idx >= NPOS) return;
    int j = idx & 63;
    int i = (idx >> 6) & 63;
    int s = (idx >> 12) % SS;
    float xv = x[idx];
    float o[8];
#pragma unroll
    for (int d = 0; d < 8; ++d) {
        float v = xv * conv_w[d];
        v = v > 0.f ? v : 0.f;
        o[d] = v + pos_s[s * 8 + d] + pos_h[d * 64 + i] + pos_w[d * 64 + j];
    }
    float4* dst = (float4*)(xt + (size_t)idx * 8);
    dst[0] = make_float4(o[0], o[1], o[2], o[3]);
    dst[1] = make_float4(o[4], o[5], o[6], o[7]);
}

// ---------------------------------------------------------------------------
// Axis attention: LINES lines per block, one thread per (line, head, row).
template <int L, int LINES, bool ACCUM>
__global__ __launch_bounds__(LINES * HH * L)
void attn_kernel(const float* __restrict__ src, float* __restrict__ dst,
                 const float* __restrict__ Wq, const float* __restrict__ Wkv,
                 const float* __restrict__ Wo, const float* __restrict__ bo,
                 int m0, int c1, int m1, int stride) {
    constexpr int NT = LINES * HH * L;
    constexpr int LL = LINES * L;
    __shared__ float4 zl4[2][LL];      // z line, quad-major: lane i -> quad i (conflict-free)
    __shared__ float4 kv4[LL][8];      // quads 0..3 = K heads, 4..7 = V heads
    __shared__ float4 olT4[HH][LL];    // attention out, head-major (conflict-free write)
    __shared__ float4 wq4[8][4];       // wq4[d][h]
    __shared__ float4 wkv4[8][8];      // wkv4[d][c]
    __shared__ float  wo_sT[8][16];    // wo_sT[d][c] = Wo[c][d]
    __shared__ float  bo_s[8];

    const int t = threadIdx.x;
    if (t < 32)  wq4[t >> 2][t & 3] = *(const float4*)(Wq + t * 4);
    if (t < 64)  wkv4[t >> 3][t & 7] = *(const float4*)(Wkv + t * 4);
    if (t < 128) wo_sT[t >> 4][t & 15] = Wo[(t & 15) * 8 + (t >> 4)];
    if (t < 8)   bo_s[t] = bo[t];

    size_t base[LINES];
#pragma unroll
    for (int ln = 0; ln < LINES; ++ln) {
        int lid = blockIdx.x * LINES + ln;
        int u0 = lid & 63;
        int rest = lid >> 6;
        int u1 = rest % c1;
        int b  = rest / c1;
        base[ln] = (size_t)b * 655360 + (size_t)u1 * m1 + (size_t)u0 * m0;
    }

    // stage z line(s): each element is a float4 (half a position's channels)
    for (int idx = t; idx < LL * 2; idx += NT) {
        int q = idx & 1, lp = idx >> 1;
        int ln = lp / L, p = lp % L;
        zl4[q][lp] = *(const float4*)(src + base[ln] + (size_t)p * stride + q * 4);
    }
    __syncthreads();

    // K,V projection: one float4 (c-quad) per loop element
    for (int idx = t; idx < LL * 8; idx += NT) {
        int c = idx & 7, lp = idx >> 3;
        float4 z0 = zl4[0][lp], z1 = zl4[1][lp];
        const float zs[8] = {z0.x, z0.y, z0.z, z0.w, z1.x, z1.y, z1.z, z1.w};
        float4 acc = make_float4(0.f, 0.f, 0.f, 0.f);
#pragma unroll
        for (int d = 0; d < 8; ++d) {
            float4 w = wkv4[d][c];
            acc.x += zs[d] * w.x; acc.y += zs[d] * w.y;
            acc.z += zs[d] * w.z; acc.w += zs[d] * w.w;
        }
        kv4[lp][c] = acc;
    }
    __syncthreads();

    // Attention: thread = (line, head, row)
    {
        const int ln = t / (HH * L);
        const int r  = t % (HH * L);
        const int h  = r / L;
        const int i  = r % L;
        const int jb = ln * L;
        float4 z0 = zl4[0][jb + i], z1 = zl4[1][jb + i];
        const float zs[8] = {z0.x, z0.y, z0.z, z0.w, z1.x, z1.y, z1.z, z1.w};
        float4 q = make_float4(0.f, 0.f, 0.f, 0.f);
#pragma unroll
        for (int d = 0; d < 8; ++d) {
            float4 w = wq4[d][h];
            q.x += zs[d] * w.x; q.y += zs[d] * w.y;
            q.z += zs[d] * w.z; q.w += zs[d] * w.w;
        }
        q.x *= 0.5f; q.y *= 0.5f; q.z *= 0.5f; q.w *= 0.5f;   // E^-0.5

        float dots[L];
        float m = -1e30f;
#pragma unroll
        for (int j = 0; j < L; ++j) {
            float4 k = kv4[jb + j][h];
            float dp = q.x * k.x + q.y * k.y + q.z * k.z + q.w * k.w;
            dots[j] = dp;
            m = fmaxf(m, dp);
        }
        float sum = 0.f;
        float4 oe = make_float4(0.f, 0.f, 0.f, 0.f);
#pragma unroll
        for (int j = 0; j < L; ++j) {
            float p = __expf(dots[j] - m);
            sum += p;
            float4 v = kv4[jb + j][4 + h];
            oe.x += p * v.x; oe.y += p * v.y;
            oe.z += p * v.z; oe.w += p * v.w;
        }
        float inv = 1.f / sum;
        oe.x *= inv; oe.y *= inv; oe.z *= inv; oe.w *= inv;
        olT4[h][jb + i] = oe;
    }
    __syncthreads();

    // Output projection (+ optional accumulate). NT % 8 == 0 -> d fixed per thread.
    {
        const int d = t & 7;
        float4 w0 = *(const float4*)&wo_sT[d][0];
        float4 w1 = *(const float4*)&wo_sT[d][4];
        float4 w2 = *(const float4*)&wo_sT[d][8];
        float4 w3 = *(const float4*)&wo_sT[d][12];
        float bod = bo_s[d];
        for (int idx = t; idx < LL * 8; idx += NT) {
            int lp = idx >> 3;
            int ln = lp / L, p = lp % L;
            float4 o0 = olT4[0][lp], o1 = olT4[1][lp];
            float4 o2 = olT4[2][lp], o3 = olT4[3][lp];
            float acc = bod
                + o0.x * w0.x + o0.y * w0.y + o0.z * w0.z + o0.w * w0.w
                + o1.x * w1.x + o1.y * w1.y + o1.z * w1.z + o1.w * w1.w
                + o2.x * w2.x + o2.y * w2.y + o2.z * w2.z + o2.w * w2.w
                + o3.x * w3.x + o3.y * w3.y + o3.z * w3.z + o3.w * w3.w;
            size_t gi = base[ln] + (size_t)p * stride + d;
            if (ACCUM) dst[gi] += acc;
            else       dst[gi] = acc;
        }
    }
}

// ---------------------------------------------------------------------------
__global__ __launch_bounds__(256)
void reduce_kernel(const float* __restrict__ z, const float* __restrict__ xt,
                   const float* __restrict__ Wc, float* __restrict__ accum) {
    const int b  = blockIdx.x >> 4;
    const int ij = ((blockIdx.x & 15) << 8) + threadIdx.x;
    float4 m0 = make_float4(-1e30f, -1e30f, -1e30f, -1e30f);
    float4 m1 = m0;
    for (int s = 0; s < SS; ++s) {
        size_t off = (((size_t)(b * SS + s)) * 4096 + ij) * 8;
        float4 a0 = *(const float4*)(z + off);
        float4 a1 = *(const float4*)(z + off + 4);
        float4 c0 = *(const float4*)(xt + off);
        float4 c1 = *(const float4*)(xt + off + 4);
        m0.x = fmaxf(m0.x, a0.x + c0.x); m0.y = fmaxf(m0.y, a0.y + c0.y);
        m0.z = fmaxf(m0.z, a0.z + c0.z); m0.w = fmaxf(m0.w, a0.w + c0.w);
        m1.x = fmaxf(m1.x, a1.x + c1.x); m1.y = fmaxf(m1.y, a1.y + c1.y);
        m1.z = fmaxf(m1.z, a1.z + c1.z); m1.w = fmaxf(m1.w, a1.w + c1.w);
    }
    float partial =
        m0.x * Wc[0 * 4096 + ij] + m0.y * Wc[1 * 4096 + ij] +
        m0.z * Wc[2 * 4096 + ij] + m0.w * Wc[3 * 4096 + ij] +
        m1.x * Wc[4 * 4096 + ij] + m1.y * Wc[5 * 4096 + ij] +
        m1.z * Wc[6 * 4096 + ij] + m1.w * Wc[7 * 4096 + ij];

    __shared__ float red[256];
    red[threadIdx.x] = partial;
    __syncthreads();
#pragma unroll
    for (int off = 128; off > 0; off >>= 1) {
        if (threadIdx.x < off) red[threadIdx.x] += red[threadIdx.x + off];
        __syncthreads();
    }
    if (threadIdx.x == 0) atomicAdd(&accum[b], red[0]);
}

__global__ void final_kernel(const float* __restrict__ accum,
                             const float* __restrict__ bc,
                             float* __restrict__ out) {
    int b = threadIdx.x;
    if (b < BB) out[b] = 1.f / (1.f + expf(-(accum[b] + bc[0])));
}

// ---------------------------------------------------------------------------
extern "C" void kernel_launch(void* const* d_in, const int* in_sizes, int n_in,
                              void* d_out, int out_size, void* d_ws, size_t ws_size,
                              hipStream_t stream) {
    const float* x      = (const float*)d_in[0];
    const float* conv_w = (const float*)d_in[1];
    const float* pos_s  = (const float*)d_in[2];
    const float* pos_h  = (const float*)d_in[3];
    const float* pos_w  = (const float*)d_in[4];
    const float* Wq     = (const float*)d_in[5];
    const float* Wkv    = (const float*)d_in[6];
    const float* Wo     = (const float*)d_in[7];
    const float* bo     = (const float*)d_in[8];
    const float* Wc     = (const float*)d_in[9];
    const float* bc     = (const float*)d_in[10];
    float* out = (float*)d_out;

    char* ws = (char*)d_ws;
    float* xt    = (float*)(ws);
    float* zA    = (float*)(ws + ZBYTES);
    float* zB    = (float*)(ws + 2 * ZBYTES);
    float* accum = (float*)(ws + 3 * ZBYTES);

    emb_kernel<<<NPOS / 256, 256, 0, stream>>>(x, conv_w, pos_s, pos_h, pos_w, xt);

    const float* cur = xt;
    float* bufs[2] = {zA, zB};
    int w = 0;
    for (int l = 0; l < NLAYER; ++l) {
        float* dstp = bufs[w];
        const float* wq0  = Wq  + (size_t)(l * 3 + 0) * 128;
        const float* wkv0 = Wkv + (size_t)(l * 3 + 0) * 256;
        const float* wo0  = Wo  + (size_t)(l * 3 + 0) * 128;
        const float* bo0  = bo  + (size_t)(l * 3 + 0) * 8;
        // a=0: attend over s (L=20), 4 lines/block
        attn_kernel<SS, 4, false><<<BB * IMM * IMM / 4, SS * 4 * HH, 0, stream>>>(
            cur, dstp, wq0, wkv0, wo0, bo0, 8, 64, 512, 32768);
        // a=1: attend over i (L=64)
        attn_kernel<IMM, 1, true><<<BB * SS * IMM, IMM * HH, 0, stream>>>(
            cur, dstp, wq0 + 128, wkv0 + 256, wo0 + 128, bo0 + 8, 8, 20, 32768, 512);
        // a=2: attend over j (L=64)
        attn_kernel<IMM, 1, true><<<BB * SS * IMM, IMM * HH, 0, stream>>>(
            cur, dstp, wq0 + 256, wkv0 + 512, wo0 + 256, bo0 + 16, 512, 20, 32768, 8);
        cur = dstp;
        w ^= 1;
    }

    hipMemsetAsync(accum, 0, BB * sizeof(float), stream);
    reduce_kernel<<<BB * 16, 256, 0, stream>>>(cur, xt, Wc, accum);
    final_kernel<<<1, 64, 0, stream>>>(accum, bc, out);
}